// Round 4
// baseline (669.268 us; speedup 1.0000x reference)
//
#include <hip/hip_runtime.h>

#define N_NODES 50000
#define N_EDGES 800000
#define D_IN    64
#define D_HID   128
#define NBLK    ((N_NODES + 255) / 256)   // 196

// ---- CSR build ----
__global__ void k_count(const int* __restrict__ rcv, int* __restrict__ deg) {
    int i = blockIdx.x * blockDim.x + threadIdx.x;
    if (i < N_EDGES) atomicAdd(&deg[rcv[i]], 1);
}

// per-256-node-block degree sums
__global__ void k_blocksum(const int* __restrict__ deg, int* __restrict__ bsum) {
    int b = blockIdx.x, t = threadIdx.x;
    int i = b * 256 + t;
    int v = (i < N_NODES) ? deg[i] : 0;
#pragma unroll
    for (int o = 32; o >= 1; o >>= 1) v += __shfl_down(v, o);
    __shared__ int s[4];
    if ((t & 63) == 0) s[t >> 6] = v;
    __syncthreads();
    if (t == 0) bsum[b] = s[0] + s[1] + s[2] + s[3];
}

// single small block: exclusive scan of 196 block sums
__global__ void k_scanb(const int* __restrict__ bsum, int* __restrict__ boff) {
    __shared__ int sh[256];
    int t = threadIdx.x;
    int v = (t < NBLK) ? bsum[t] : 0;
    sh[t] = v;
    __syncthreads();
    for (int d = 1; d < 256; d <<= 1) {
        int u = (t >= d) ? sh[t - d] : 0;
        __syncthreads();
        sh[t] += u;
        __syncthreads();
    }
    boff[t] = sh[t] - v;   // exclusive
}

// per-block local scan + global offset -> off/cursor/inv
__global__ void k_offsets(const int* __restrict__ deg, const int* __restrict__ boff,
                          int* __restrict__ off, int* __restrict__ cursor,
                          float* __restrict__ inv) {
    __shared__ int sh[256];
    int b = blockIdx.x, t = threadIdx.x, i = b * 256 + t;
    int d = (i < N_NODES) ? deg[i] : 0;
    sh[t] = d;
    __syncthreads();
    for (int o = 1; o < 256; o <<= 1) {
        int u = (t >= o) ? sh[t - o] : 0;
        __syncthreads();
        sh[t] += u;
        __syncthreads();
    }
    if (i < N_NODES) {
        int excl = boff[b] + sh[t] - d;
        off[i] = excl;
        cursor[i] = excl;
        inv[i] = d > 0 ? 1.0f / (float)d : 0.0f;
    }
    if (b == 0 && t == 0) off[N_NODES] = N_EDGES;
}

// fill CSR with packed (sender, weight-bits) -> one 8B element per edge
__global__ void k_fill(const int* __restrict__ snd, const int* __restrict__ rcv,
                       const float* __restrict__ w,
                       int* __restrict__ cursor, int2* __restrict__ e_sw) {
    int i = blockIdx.x * blockDim.x + threadIdx.x;
    if (i >= N_EDGES) return;
    int r = rcv[i];
    int p = atomicAdd(&cursor[r], 1);
    e_sw[p] = make_int2(snd[i], __float_as_int(w[i]));
}

// ---- fused layer ----
// One wave per node. float2-per-lane feature layout:
//   DIN=128: lane l holds feats {2l, 2l+1}; one dwordx2 load = full row.
//   DIN=64 : half-wave g=lane>>5 handles alternating edges; feats {2(l&31), ...};
//            halves combined via shfl_xor(32) at the end.
// MLP (DOUT=128) via compile-time-unrolled shfl row-broadcast.
template<int DIN, bool RELU, bool DO_MLP>
__global__ __launch_bounds__(256) void k_layer(
        const float* __restrict__ h,
        const int* __restrict__ off,
        const int2* __restrict__ e_sw,
        const float* __restrict__ inv,
        const float* __restrict__ eps, int li,
        const float* __restrict__ W,
        const float* __restrict__ b,
        float* __restrict__ out) {
    int wave = threadIdx.x >> 6;
    int lane = threadIdx.x & 63;
    int n = blockIdx.x * 4 + wave;
    if (n >= N_NODES) return;

    float se = 1.0f + eps[li];
    se = se > 0.0f ? se : 0.0f;
    float id = inv[n];
    int e0 = off[n], e1 = off[n + 1];

    float px = 0.0f, py = 0.0f;

    if constexpr (DIN == 128) {
        const int f = lane * 2;
        int e = e0;
        for (; e + 8 <= e1; e += 8) {              // 8 independent 512B gathers in flight
            int2 s0 = e_sw[e+0], s1 = e_sw[e+1], s2 = e_sw[e+2], s3 = e_sw[e+3];
            int2 s4 = e_sw[e+4], s5 = e_sw[e+5], s6 = e_sw[e+6], s7 = e_sw[e+7];
            float2 a0 = *(const float2*)(h + (size_t)s0.x * 128 + f);
            float2 a1 = *(const float2*)(h + (size_t)s1.x * 128 + f);
            float2 a2 = *(const float2*)(h + (size_t)s2.x * 128 + f);
            float2 a3 = *(const float2*)(h + (size_t)s3.x * 128 + f);
            float2 a4 = *(const float2*)(h + (size_t)s4.x * 128 + f);
            float2 a5 = *(const float2*)(h + (size_t)s5.x * 128 + f);
            float2 a6 = *(const float2*)(h + (size_t)s6.x * 128 + f);
            float2 a7 = *(const float2*)(h + (size_t)s7.x * 128 + f);
            float w0 = __int_as_float(s0.y), w1 = __int_as_float(s1.y);
            float w2 = __int_as_float(s2.y), w3 = __int_as_float(s3.y);
            float w4 = __int_as_float(s4.y), w5 = __int_as_float(s5.y);
            float w6 = __int_as_float(s6.y), w7 = __int_as_float(s7.y);
            px += a0.x*w0 + a1.x*w1 + a2.x*w2 + a3.x*w3 + a4.x*w4 + a5.x*w5 + a6.x*w6 + a7.x*w7;
            py += a0.y*w0 + a1.y*w1 + a2.y*w2 + a3.y*w3 + a4.y*w4 + a5.y*w5 + a6.y*w6 + a7.y*w7;
        }
        for (; e + 2 <= e1; e += 2) {
            int2 s0 = e_sw[e], s1 = e_sw[e+1];
            float2 a0 = *(const float2*)(h + (size_t)s0.x * 128 + f);
            float2 a1 = *(const float2*)(h + (size_t)s1.x * 128 + f);
            float w0 = __int_as_float(s0.y), w1 = __int_as_float(s1.y);
            px += a0.x*w0 + a1.x*w1;
            py += a0.y*w0 + a1.y*w1;
        }
        if (e < e1) {
            int2 s0 = e_sw[e];
            float2 a0 = *(const float2*)(h + (size_t)s0.x * 128 + f);
            float w0 = __int_as_float(s0.y);
            px += a0.x*w0; py += a0.y*w0;
        }
    } else {
        const int g = lane >> 5;
        const int f = (lane & 31) * 2;
        int e = e0;
        for (; e + 8 <= e1; e += 8) {              // each half-wave: 4 edges
            int2 s0 = e_sw[e+0+g], s1 = e_sw[e+2+g], s2 = e_sw[e+4+g], s3 = e_sw[e+6+g];
            float2 a0 = *(const float2*)(h + (size_t)s0.x * 64 + f);
            float2 a1 = *(const float2*)(h + (size_t)s1.x * 64 + f);
            float2 a2 = *(const float2*)(h + (size_t)s2.x * 64 + f);
            float2 a3 = *(const float2*)(h + (size_t)s3.x * 64 + f);
            float w0 = __int_as_float(s0.y), w1 = __int_as_float(s1.y);
            float w2 = __int_as_float(s2.y), w3 = __int_as_float(s3.y);
            px += a0.x*w0 + a1.x*w1 + a2.x*w2 + a3.x*w3;
            py += a0.y*w0 + a1.y*w1 + a2.y*w2 + a3.y*w3;
        }
        for (int ee = e + g; ee < e1; ee += 2) {
            int2 s0 = e_sw[ee];
            float2 a0 = *(const float2*)(h + (size_t)s0.x * 64 + f);
            float w0 = __int_as_float(s0.y);
            px += a0.x*w0; py += a0.y*w0;
        }
        px += __shfl_xor(px, 32);
        py += __shfl_xor(py, 32);
    }

    const int fh = (DIN == 128) ? lane * 2 : (lane & 31) * 2;
    float2 hv = *(const float2*)(h + (size_t)n * DIN + fh);
    float prex = hv.x * se + px * id;
    float prey = hv.y * se + py * id;

    if constexpr (!DO_MLP) {
        *(float2*)(out + (size_t)n * DIN + lane * 2) = make_float2(prex, prey);
        return;
    }

    float2 acc = *(const float2*)(b + lane * 2);
#pragma unroll
    for (int d = 0; d < DIN; ++d) {
        float pd = __shfl((d & 1) ? prey : prex, d >> 1);
        float2 wv = *(const float2*)(W + d * 128 + lane * 2);
        acc.x += pd * wv.x;
        acc.y += pd * wv.y;
    }
    if (RELU) {
        acc.x = acc.x > 0.0f ? acc.x : 0.0f;
        acc.y = acc.y > 0.0f ? acc.y : 0.0f;
    }
    *(float2*)(out + (size_t)n * 128 + lane * 2) = acc;
}

// standalone per-row MLP (layer-2 tail), float2 layout
__global__ __launch_bounds__(256) void k_mlp(const float* __restrict__ h,
                                             const float* __restrict__ W,
                                             const float* __restrict__ b,
                                             float* __restrict__ out) {
    int wave = threadIdx.x >> 6;
    int lane = threadIdx.x & 63;
    int n = blockIdx.x * 4 + wave;
    if (n >= N_NODES) return;

    float2 pre = *(const float2*)(h + (size_t)n * 128 + lane * 2);
    float2 acc = *(const float2*)(b + lane * 2);
#pragma unroll
    for (int d = 0; d < 128; ++d) {
        float pd = __shfl((d & 1) ? pre.y : pre.x, d >> 1);
        float2 wv = *(const float2*)(W + d * 128 + lane * 2);
        acc.x += pd * wv.x;
        acc.y += pd * wv.y;
    }
    *(float2*)(out + (size_t)n * 128 + lane * 2) = acc;
}

extern "C" void kernel_launch(void* const* d_in, const int* in_sizes, int n_in,
                              void* d_out, int out_size, void* d_ws, size_t ws_size,
                              hipStream_t stream) {
    const float* h0  = (const float*)d_in[0];
    const float* wts = (const float*)d_in[1];
    const int*   snd = (const int*)d_in[2];
    const int*   rcv = (const int*)d_in[3];
    const float* W0  = (const float*)d_in[4];
    const float* b0  = (const float*)d_in[5];
    const float* W1  = (const float*)d_in[6];
    const float* b1  = (const float*)d_in[7];
    const float* W2  = (const float*)d_in[8];
    const float* b2  = (const float*)d_in[9];
    const float* eps = (const float*)d_in[10];

    float* out0 = (float*)d_out;                  // node_embeddings
    float* out1 = out0 + (size_t)N_NODES * D_HID; // final h

    // ws layout (ints): deg[50000] bsum[256] boff[256] off[50002 pad] cursor[50000] inv[50000] | e_sw int2
    int*   deg    = (int*)d_ws;
    int*   bsum   = deg + N_NODES;
    int*   boff   = bsum + 256;
    int*   off    = boff + 256;
    int*   cursor = off + N_NODES + 2;            // +2 keeps e_sw 8B-aligned
    float* inv    = (float*)(cursor + N_NODES);
    int2*  e_sw   = (int2*)(inv + N_NODES);

    hipMemsetAsync(deg, 0, (size_t)N_NODES * sizeof(int), stream);
    k_count<<<(N_EDGES + 255) / 256, 256, 0, stream>>>(rcv, deg);
    k_blocksum<<<NBLK, 256, 0, stream>>>(deg, bsum);
    k_scanb<<<1, 256, 0, stream>>>(bsum, boff);
    k_offsets<<<NBLK, 256, 0, stream>>>(deg, boff, off, cursor, inv);
    k_fill<<<(N_EDGES + 255) / 256, 256, 0, stream>>>(snd, rcv, wts, cursor, e_sw);

    // L0: h0(64) -> out0(128), relu
    k_layer<D_IN, true, true><<<(N_NODES + 3) / 4, 256, 0, stream>>>(
        h0, off, e_sw, inv, eps, 0, W0, b0, out0);
    // L1: out0 -> out1, relu
    k_layer<D_HID, true, true><<<(N_NODES + 3) / 4, 256, 0, stream>>>(
        out0, off, e_sw, inv, eps, 1, W1, b1, out1);
    // L2a: gather+update only: out1 -> out0 (= node_embeddings)
    k_layer<D_HID, false, false><<<(N_NODES + 3) / 4, 256, 0, stream>>>(
        out1, off, e_sw, inv, eps, 2, nullptr, nullptr, out0);
    // L2b: final MLP (no relu): out0 -> out1
    k_mlp<<<(N_NODES + 3) / 4, 256, 0, stream>>>(out0, W2, b2, out1);
}

// Round 7
// 495.836 us; speedup vs baseline: 1.3498x; 1.3498x over previous
//
#include <hip/hip_runtime.h>

#define N_NODES 50000
#define N_EDGES 800000
#define D_IN    64
#define D_HID   128
#define NBLK    ((N_NODES + 255) / 256)   // 196

__device__ __forceinline__ float bf2f(unsigned short u) {
    return __uint_as_float(((unsigned)u) << 16);
}

// ---- CSR build ----
__global__ void k_count(const int* __restrict__ rcv, int* __restrict__ deg) {
    int i = blockIdx.x * blockDim.x + threadIdx.x;
    if (i < N_EDGES) atomicAdd(&deg[rcv[i]], 1);
}

__global__ void k_blocksum(const int* __restrict__ deg, int* __restrict__ bsum) {
    int b = blockIdx.x, t = threadIdx.x;
    int i = b * 256 + t;
    int v = (i < N_NODES) ? deg[i] : 0;
#pragma unroll
    for (int o = 32; o >= 1; o >>= 1) v += __shfl_down(v, o);
    __shared__ int s[4];
    if ((t & 63) == 0) s[t >> 6] = v;
    __syncthreads();
    if (t == 0) bsum[b] = s[0] + s[1] + s[2] + s[3];
}

__global__ void k_scanb(const int* __restrict__ bsum, int* __restrict__ boff) {
    __shared__ int sh[256];
    int t = threadIdx.x;
    int v = (t < NBLK) ? bsum[t] : 0;
    sh[t] = v;
    __syncthreads();
    for (int d = 1; d < 256; d <<= 1) {
        int u = (t >= d) ? sh[t - d] : 0;
        __syncthreads();
        sh[t] += u;
        __syncthreads();
    }
    boff[t] = sh[t] - v;   // exclusive
}

__global__ void k_offsets(const int* __restrict__ deg, const int* __restrict__ boff,
                          int* __restrict__ off, int* __restrict__ cursor,
                          float* __restrict__ inv) {
    __shared__ int sh[256];
    int b = blockIdx.x, t = threadIdx.x, i = b * 256 + t;
    int d = (i < N_NODES) ? deg[i] : 0;
    sh[t] = d;
    __syncthreads();
    for (int o = 1; o < 256; o <<= 1) {
        int u = (t >= o) ? sh[t - o] : 0;
        __syncthreads();
        sh[t] += u;
        __syncthreads();
    }
    if (i < N_NODES) {
        int excl = boff[b] + sh[t] - d;
        off[i] = excl;
        cursor[i] = excl;
        inv[i] = d > 0 ? 1.0f / (float)d : 0.0f;
    }
    if (b == 0 && t == 0) off[N_NODES] = N_EDGES;
}

__global__ void k_fill(const int* __restrict__ snd, const int* __restrict__ rcv,
                       const float* __restrict__ w,
                       int* __restrict__ cursor,
                       int* __restrict__ e_snd, float* __restrict__ e_w) {
    int i = blockIdx.x * blockDim.x + threadIdx.x;
    if (i >= N_EDGES) return;
    int r = rcv[i];
    int p = atomicAdd(&cursor[r], 1);
    e_snd[p] = snd[i];
    e_w[p]   = w[i];
}

// ---- fp32 -> bf16 (RNE) pair-packed conversion: nfloat2 = count/2 threads ----
__global__ void k_tobf(const float* __restrict__ src, unsigned int* __restrict__ dst,
                       int npairs) {
    int i = blockIdx.x * blockDim.x + threadIdx.x;
    if (i >= npairs) return;
    float2 v = *(const float2*)(src + (size_t)i * 2);
    unsigned ux = __float_as_uint(v.x);
    unsigned uy = __float_as_uint(v.y);
    unsigned bx = (ux + 0x7FFFu + ((ux >> 16) & 1u)) >> 16;
    unsigned by = (uy + 0x7FFFu + ((uy >> 16) & 1u)) >> 16;
    dst[i] = bx | (by << 16);
}

// ---- fused layer (round-3 proven access pattern; gather source is bf16) ----
// One wave per node; lane l holds feature(s) l (+64k). Neighbor rows read from
// bf16 copy hb (halves cache lines); residual + MLP in fp32.
template<int DIN, int DOUT, bool RELU, bool DO_MLP>
__global__ __launch_bounds__(256) void k_layer(
        const float* __restrict__ h,
        const unsigned short* __restrict__ hb,
        const int* __restrict__ off,
        const int* __restrict__ e_snd,
        const float* __restrict__ e_w,
        const float* __restrict__ inv,
        const float* __restrict__ eps, int li,
        const float* __restrict__ W,
        const float* __restrict__ b,
        float* __restrict__ out) {
    constexpr int K = DIN / 64;
    int wave = threadIdx.x >> 6;
    int lane = threadIdx.x & 63;
    int n = blockIdx.x * (blockDim.x >> 6) + wave;
    if (n >= N_NODES) return;

    float pool[K];
#pragma unroll
    for (int k = 0; k < K; ++k) pool[k] = 0.0f;

    int e0 = off[n], e1 = off[n + 1];
    int e = e0;
    for (; e + 1 < e1; e += 2) {          // unroll-2 for load ILP
        int s0 = e_snd[e], s1 = e_snd[e + 1];
        float w0 = e_w[e], w1 = e_w[e + 1];
        const unsigned short* p0 = hb + (size_t)s0 * DIN;
        const unsigned short* p1 = hb + (size_t)s1 * DIN;
        float a0[K], a1[K];
#pragma unroll
        for (int k = 0; k < K; ++k) { a0[k] = bf2f(p0[lane + 64 * k]); a1[k] = bf2f(p1[lane + 64 * k]); }
#pragma unroll
        for (int k = 0; k < K; ++k) pool[k] += a0[k] * w0 + a1[k] * w1;
    }
    if (e < e1) {
        int s0 = e_snd[e]; float w0 = e_w[e];
        const unsigned short* p0 = hb + (size_t)s0 * DIN;
#pragma unroll
        for (int k = 0; k < K; ++k) pool[k] += bf2f(p0[lane + 64 * k]) * w0;
    }

    float se = 1.0f + eps[li];
    se = se > 0.0f ? se : 0.0f;           // relu(1+eps)
    float id = inv[n];
    const float* hr = h + (size_t)n * DIN;

    float pre[K];
#pragma unroll
    for (int k = 0; k < K; ++k) pre[k] = hr[lane + 64 * k] * se + pool[k] * id;

    if (!DO_MLP) {
        float* orow = out + (size_t)n * DIN;
#pragma unroll
        for (int k = 0; k < K; ++k) orow[lane + 64 * k] = pre[k];
        return;
    }

    float acc[DOUT / 64];
#pragma unroll
    for (int k = 0; k < DOUT / 64; ++k) acc[k] = b[lane + 64 * k];
#pragma unroll
    for (int d = 0; d < DIN; ++d) {
        float pd = __shfl(pre[d >> 6], d & 63);
#pragma unroll
        for (int k = 0; k < DOUT / 64; ++k)
            acc[k] += pd * W[d * DOUT + lane + 64 * k];
    }
    float* orow = out + (size_t)n * DOUT;
#pragma unroll
    for (int k = 0; k < DOUT / 64; ++k) {
        float v = acc[k];
        if (RELU) v = v > 0.0f ? v : 0.0f;
        orow[lane + 64 * k] = v;
    }
}

// ---- standalone per-row MLP (layer-2 tail; round-3 proven) ----
template<int DIN, int DOUT, bool RELU>
__global__ __launch_bounds__(256) void k_mlp(const float* __restrict__ h,
                                             const float* __restrict__ W,
                                             const float* __restrict__ b,
                                             float* __restrict__ out) {
    int wave = threadIdx.x >> 6;
    int lane = threadIdx.x & 63;
    int n = blockIdx.x * (blockDim.x >> 6) + wave;
    if (n >= N_NODES) return;

    const float* hr = h + (size_t)n * DIN;
    float pre[DIN / 64];
#pragma unroll
    for (int k = 0; k < DIN / 64; ++k) pre[k] = hr[lane + 64 * k];

    float acc[DOUT / 64];
#pragma unroll
    for (int k = 0; k < DOUT / 64; ++k) acc[k] = b[lane + 64 * k];
#pragma unroll
    for (int d = 0; d < DIN; ++d) {
        float pd = __shfl(pre[d >> 6], d & 63);
#pragma unroll
        for (int k = 0; k < DOUT / 64; ++k)
            acc[k] += pd * W[d * DOUT + lane + 64 * k];
    }
    float* orow = out + (size_t)n * DOUT;
#pragma unroll
    for (int k = 0; k < DOUT / 64; ++k) {
        float v = acc[k];
        if (RELU) v = v > 0.0f ? v : 0.0f;
        orow[lane + 64 * k] = v;
    }
}

extern "C" void kernel_launch(void* const* d_in, const int* in_sizes, int n_in,
                              void* d_out, int out_size, void* d_ws, size_t ws_size,
                              hipStream_t stream) {
    const float* h0  = (const float*)d_in[0];
    const float* wts = (const float*)d_in[1];
    const int*   snd = (const int*)d_in[2];
    const int*   rcv = (const int*)d_in[3];
    const float* W0  = (const float*)d_in[4];
    const float* b0  = (const float*)d_in[5];
    const float* W1  = (const float*)d_in[6];
    const float* b1  = (const float*)d_in[7];
    const float* W2  = (const float*)d_in[8];
    const float* b2  = (const float*)d_in[9];
    const float* eps = (const float*)d_in[10];

    float* out0 = (float*)d_out;                  // node_embeddings
    float* out1 = out0 + (size_t)N_NODES * D_HID; // final h

    // ws layout (~20 MB): deg|bsum|boff|off|cursor|inv|e_snd|e_w|hb
    int*   deg    = (int*)d_ws;
    int*   bsum   = deg + N_NODES;
    int*   boff   = bsum + 256;
    int*   off    = boff + 256;
    int*   cursor = off + N_NODES + 2;
    float* inv    = (float*)(cursor + N_NODES);
    int*   e_snd  = (int*)(inv + N_NODES);
    float* e_w    = (float*)(e_snd + N_EDGES);
    unsigned int* hb32 = (unsigned int*)(e_w + N_EDGES);   // bf16 rows, pair-packed
    unsigned short* hb = (unsigned short*)hb32;

    hipMemsetAsync(deg, 0, (size_t)N_NODES * sizeof(int), stream);
    k_count<<<(N_EDGES + 255) / 256, 256, 0, stream>>>(rcv, deg);
    k_blocksum<<<NBLK, 256, 0, stream>>>(deg, bsum);
    k_scanb<<<1, 256, 0, stream>>>(bsum, boff);
    k_offsets<<<NBLK, 256, 0, stream>>>(deg, boff, off, cursor, inv);
    k_fill<<<(N_EDGES + 255) / 256, 256, 0, stream>>>(snd, rcv, wts, cursor, e_snd, e_w);

    // L0: h0(64) -> out0(128), relu
    {
        int np = N_NODES * D_IN / 2;
        k_tobf<<<(np + 255) / 256, 256, 0, stream>>>(h0, hb32, np);
    }
    k_layer<D_IN, D_HID, true, true><<<N_NODES / 4, 256, 0, stream>>>(
        h0, hb, off, e_snd, e_w, inv, eps, 0, W0, b0, out0);

    // L1: out0 -> out1, relu
    {
        int np = N_NODES * D_HID / 2;
        k_tobf<<<(np + 255) / 256, 256, 0, stream>>>(out0, hb32, np);
    }
    k_layer<D_HID, D_HID, true, true><<<N_NODES / 4, 256, 0, stream>>>(
        out0, hb, off, e_snd, e_w, inv, eps, 1, W1, b1, out1);

    // L2a: gather+update only: out1 -> out0 (= node_embeddings)
    {
        int np = N_NODES * D_HID / 2;
        k_tobf<<<(np + 255) / 256, 256, 0, stream>>>(out1, hb32, np);
    }
    k_layer<D_HID, D_HID, false, false><<<N_NODES / 4, 256, 0, stream>>>(
        out1, hb, off, e_snd, e_w, inv, eps, 2, nullptr, nullptr, out0);

    // L2b: final MLP (no relu): out0 -> out1
    k_mlp<D_HID, D_HID, false><<<N_NODES / 4, 256, 0, stream>>>(out0, W2, b2, out1);
}